// Round 12
// baseline (174.106 us; speedup 1.0000x reference)
//
#include <hip/hip_runtime.h>
#include <math.h>

#define B_    256
#define C_    22
#define T_    1000
#define NB_   6
#define E_    6
#define MNB_  48
#define POOL_ 125
#define TP_   8
#define NC_   9
#define FEAT_ 384   // MNB_*TP_

#define PQ_   352    // plane length; x[m] lives at (plane (m+24)%3, q (m+24)/3)
#define NTH   512
#define CH_   11     // channels per block (c-half)

// Load 4 aligned float4 (16 floats) from plane pp at element base 4*tileL+Aoff.
#define LOADP(F, pp, Aoff)                                                   \
    {                                                                        \
        const float4* pb = (const float4*)&bw[pp][4*tileL + (Aoff)];         \
        float4 q0 = pb[0], q1 = pb[1], q2 = pb[2], q3 = pb[3];               \
        *(float4*)&F[0]  = q0; *(float4*)&F[4]  = q1;                        \
        *(float4*)&F[8]  = q2; *(float4*)&F[12] = q3;                        \
    }

// Apply taps of BOTH nb of the pair to window F.
#define TAPS(F, idx0, j0, nj)                                                \
    _Pragma("unroll")                                                        \
    for (int a = 0; a < (nj); ++a) {                                         \
        const float ca = ckA[(j0) + 3*a];                                    \
        const float cb = ckB[(j0) + 3*a];                                    \
        sa0 = fmaf(ca, F[(idx0) + a    ], sa0);                              \
        sa1 = fmaf(ca, F[(idx0) + a + 1], sa1);                              \
        sa2 = fmaf(ca, F[(idx0) + a + 2], sa2);                              \
        sa3 = fmaf(ca, F[(idx0) + a + 3], sa3);                              \
        sb0 = fmaf(cb, F[(idx0) + a    ], sb0);                              \
        sb1 = fmaf(cb, F[(idx0) + a + 1], sb1);                              \
        sb2 = fmaf(cb, F[(idx0) + a + 2], sb2);                              \
        sb3 = fmaf(cb, F[(idx0) + a + 3], sb3);                              \
    }

// One pair-blocked round: rr is wave-uniform (runtime), pair/tile per lane.
// Accumulates over this block's CH_ channels, then LDS-atomic adds into the
// 48 pooled partials (skipping special t's via the tile mask).
#define ROUND_BODY(ACT, RRV, PAIRV, TILEV)                                   \
    if (ACT) {                                                               \
        const int rrL = (RRV);                                               \
        const int tileL = (TILEV);                                           \
        const int nb0 = 2*(PAIRV), nb1 = nb0 + 1;                            \
        float ckA[29], ckB[29];                                              \
        _Pragma("unroll")                                                    \
        for (int t2 = 0; t2 < 29; ++t2) {                                    \
            ckA[t2] = ckl[rrL][nb0][t2];                                     \
            ckB[t2] = ckl[rrL][nb1][t2];                                     \
        }                                                                    \
        const float scA = sbn6[nb0][0], biA = sbn6[nb0][1];                  \
        const float scB = sbn6[nb1][0], biB = sbn6[nb1][1];                  \
        float aA0=0.f,aA1=0.f,aA2=0.f,aA3=0.f;                               \
        float aB0=0.f,aB1=0.f,aB2=0.f,aB3=0.f;                               \
        _Pragma("unroll 1")                                                  \
        for (int c = 0; c < CH_; ++c) {                                      \
            const float (*bw)[PQ_] = pl[c];                                  \
            float f0[16], f1[16], f2[16];                                    \
            float sa0=0.f,sa1=0.f,sa2=0.f,sa3=0.f;                           \
            float sb0=0.f,sb1=0.f,sb2=0.f,sb3=0.f;                           \
            if (rrL == 0) {                                                  \
                LOADP(f0,2,0)    TAPS(f0,3,0,10)                             \
                LOADP(f1,0,4)    TAPS(f1,0,1,10)                             \
                LOADP(f2,1,4)    TAPS(f2,0,2,9)                              \
            } else if (rrL == 1) {                                           \
                LOADP(f0,1,-332) TAPS(f0,2,0,10)                             \
                LOADP(f1,2,-332) TAPS(f1,2,1,10)                             \
                LOADP(f2,0,-332) TAPS(f2,3,2,9)                              \
            } else {                                                         \
                LOADP(f0,0,-664) TAPS(f0,1,0,10)                             \
                LOADP(f1,1,-664) TAPS(f1,1,1,10)                             \
                LOADP(f2,2,-664) TAPS(f2,1,2,9)                              \
            }                                                                \
            const float swA = sws6[nb0][c], swB = sws6[nb1][c];              \
            aA0 += fmaxf(fmaf(sa0, scA, biA), 0.f) * swA;                    \
            aA1 += fmaxf(fmaf(sa1, scA, biA), 0.f) * swA;                    \
            aA2 += fmaxf(fmaf(sa2, scA, biA), 0.f) * swA;                    \
            aA3 += fmaxf(fmaf(sa3, scA, biA), 0.f) * swA;                    \
            aB0 += fmaxf(fmaf(sb0, scB, biB), 0.f) * swB;                    \
            aB1 += fmaxf(fmaf(sb1, scB, biB), 0.f) * swB;                    \
            aB2 += fmaxf(fmaf(sb2, scB, biB), 0.f) * swB;                    \
            aB3 += fmaxf(fmaf(sb3, scB, biB), 0.f) * swB;                    \
        }                                                                    \
        int skip = 0;                                                        \
        if (tileL == 0) skip = 1; else if (tileL == 83) skip = 3;            \
        else if (tileL == 166) skip = 12; else if (tileL == 249) skip = 8;   \
        const int t0 = 4 * tileL;                                            \
        const float vA[4] = {aA0,aA1,aA2,aA3};                               \
        const float vB[4] = {aB0,aB1,aB2,aB3};                               \
        _Pragma("unroll")                                                    \
        for (int o = 0; o < 4; ++o) {                                        \
            if (!((skip >> o) & 1)) {                                        \
                const int wdw = (t0 + o) / 125;                              \
                atomicAdd(&psum[nb0*TP_ + wdw], vA[o]);                      \
                atomicAdd(&psum[nb1*TP_ + wdw], vB[o]);                      \
            }                                                                \
        }                                                                    \
    }

// ---------------------------------------------------------------------------
// Stage 1 (R12): grid 512 = (b, c-half). 512 threads, __launch_bounds__(512,4)
// -> 2 blocks/CU (16 waves, 4/SIMD), VGPR cap 128 >= pair demand (~124): no
// spill. ReLU is per-channel, so channel-partial POOLED sums are exact:
// block outputs 48 pooled partials + 36 corr partials (tiny ws). Planes
// staged once; main loop barrier-free, pair-blocked, wave-uniform regions.
// ---------------------------------------------------------------------------
__global__ __launch_bounds__(NTH, 4) void fb_stage1(
    const float* __restrict__ x,
    const float* __restrict__ fir,
    const float* __restrict__ w3,
    const float* __restrict__ w5,
    const float* __restrict__ w7,
    const float* __restrict__ bn_g, const float* __restrict__ bn_b,
    const float* __restrict__ bn_m, const float* __restrict__ bn_v,
    const float* __restrict__ sconv_w,
    float* __restrict__ hpP, float* __restrict__ corrP)
{
    const int b    = blockIdx.x >> 1;
    const int half = blockIdx.x & 1;
    const int tid  = threadIdx.x;

    __shared__ __align__(16) float pl[CH_][3][PQ_];  // 46.5 KB
    __shared__ float firs6[NB_][21];
    __shared__ float w3s6[NB_][3];
    __shared__ float w5s6[NB_][5];
    __shared__ float w7s6[NB_][7];
    __shared__ float sws6[NB_][CH_];     // this half's channels
    __shared__ float sbn6[NB_][2];
    __shared__ float ckl[3][NB_][29];
    __shared__ float xbv[NB_][CH_][13];
    __shared__ float term[NB_][6][CH_];
    __shared__ float psum[MNB_];         // pooled partial sums (atomic)

    const float* xbase = x + (size_t)b * (C_ * T_) + half * (CH_ * T_);

    // ---- weights to LDS + psum zero ----
    if (tid < 126)                      { int nb=tid/21; firs6[nb][tid%21] = fir[tid]; }
    else if (tid >= 128 && tid < 146)   { int k=tid-128; w3s6[k/3][k%3] = w3[k]; }
    else if (tid >= 160 && tid < 190)   { int k=tid-160; w5s6[k/5][k%5] = w5[k]; }
    else if (tid >= 192 && tid < 234)   { int k=tid-192; w7s6[k/7][k%7] = w7[k]; }
    else if (tid >= 240 && tid < 306)   { int k=tid-240; sws6[k/CH_][k%CH_] = sconv_w[(k/CH_)*C_ + half*CH_ + k%CH_]; }
    else if (tid >= 320 && tid < 326) {
        const int nb = tid - 320;
        float sc = bn_g[nb] * rsqrtf(bn_v[nb] + 1e-5f);
        sbn6[nb][0] = sc * (1.f/3.f);        // folds the /3 of the triple-mean
        sbn6[nb][1] = bn_b[nb] - bn_m[nb] * sc;
    }
    else if (tid >= 448 && tid < 496)   psum[tid - 448] = 0.f;

    // ---- stage this half's 11 channels in plane order ----
    #pragma unroll
    for (int k = 0; k < 6; ++k) {
        const int idx = tid + k * NTH;            // 0..3071
        if (idx < CH_ * 264) {                    // 2904
            const int cl  = idx / 264;
            const int rem = idx % 264;
            const int p   = rem / 88;
            const int q0  = (rem % 88) * 4;
            const float* xr = xbase + cl * T_;
            float v[4];
            #pragma unroll
            for (int i = 0; i < 4; ++i) {
                const int m  = 3 * (q0 + i) + p - 24;
                const int mc = m < 0 ? 0 : (m > 999 ? 999 : m);
                const float val = xr[mc];
                v[i] = ((unsigned)m < 1000u) ? val : 0.f;
            }
            *(float4*)&pl[cl][p][q0] = make_float4(v[0], v[1], v[2], v[3]);
        }
    }
    __syncthreads();   // S1: planes + weights visible

    // ---- build ckl (522) ∥ phaseB: boundary FIR dots (858) ----
    for (int idx = tid; idx < 522; idx += NTH) {
        const int combo = idx / 29, jj = idx % 29;
        const int rr2 = combo / 6, nb = combo % 6;
        const float* wk = (rr2 == 0) ? w3s6[nb] : (rr2 == 1 ? w5s6[nb] : w7s6[nb]);
        const int K  = (rr2 == 0) ? 3 : (rr2 == 1 ? 5 : 7);
        const int pk = K >> 1;
        float s = 0.f;
        #pragma unroll
        for (int oi = 0; oi < 9; ++oi) {
            const int o = oi - 3;
            float we = 0.f;
            for (int k = 0; k < 7; ++k) {
                if (k < K) {
                    const int jx = o + pk - k;
                    if (jx >= 0 && jx < 3) we += wk[k];
                }
            }
            const int i = jj - oi;
            if (i >= 0 && i < 21) s = fmaf(we, firs6[nb][i], s);
        }
        ckl[rr2][nb][jj] = s;
    }
    for (int idx = tid; idx < NB_ * CH_ * 13; idx += NTH) {    // 858
        const int nb  = idx / (CH_ * 13);
        const int rem = idx % (CH_ * 13);
        const int cl  = rem / 13, pos = rem % 13;
        const int m   = (pos < 7) ? pos : (987 + pos);         // 0..6, 994..999
        int mm = m + 14;                                       // (m-10)+24
        int q  = mm / 3, p = mm - 3 * q;
        float s = 0.f;
        #pragma unroll
        for (int i = 0; i < 21; ++i) {
            s = fmaf(firs6[nb][i], pl[cl][p][q], s);
            ++p; if (p == 3) { p = 0; ++q; }
        }
        xbv[nb][cl][pos] = s;
    }
    __syncthreads();   // S2: ckl + xbv visible

    // ---- phaseC: partial special outputs (this half's channels) ----
    if (tid < NB_ * 6 * CH_) {                    // 396
        const int nb  = tid / (6 * CH_);
        const int rem = tid % (6 * CH_);
        const int tix = rem / CH_, cl = rem % CH_;
        const float* X  = xbv[nb][cl];  // X[0..6]=xb(0..6), X[7..12]=xb(994..999)
        const float* W3 = w3s6[nb];
        const float* W5 = w5s6[nb];
        const float* W7 = w7s6[nb];
        float s;
        switch (tix) {
        case 0:
            s = W3[1]*X[0]+W3[2]*X[1]
              + W3[0]*X[0]+W3[1]*X[1]+W3[2]*X[2]
              + W3[0]*X[1]+W3[1]*X[2]+W3[2]*X[3];
            break;
        case 1:
            s = W3[0]*X[8]+W3[1]*X[9]+W3[2]*X[10]
              + W3[0]*X[9]+W3[1]*X[10]+W3[2]*X[11]
              + W3[0]*X[10]+W3[1]*X[11]+W3[2]*X[12];
            break;
        case 2:
            s = W3[0]*X[11]+W3[1]*X[12]
              + W5[2]*X[0]+W5[3]*X[1]+W5[4]*X[2]
              + W5[1]*X[0]+W5[2]*X[1]+W5[3]*X[2]+W5[4]*X[3];
            break;
        case 3:
            s = W5[0]*X[9]+W5[1]*X[10]+W5[2]*X[11]+W5[3]*X[12]
              + W5[0]*X[10]+W5[1]*X[11]+W5[2]*X[12]
              + W7[3]*X[0]+W7[4]*X[1]+W7[5]*X[2]+W7[6]*X[3];
            break;
        case 4:
            s = W7[2]*X[0]+W7[3]*X[1]+W7[4]*X[2]+W7[5]*X[3]+W7[6]*X[4]
              + W7[1]*X[0]+W7[2]*X[1]+W7[3]*X[2]+W7[4]*X[3]+W7[5]*X[4]+W7[6]*X[5]
              + W7[0]*X[0]+W7[1]*X[1]+W7[2]*X[2]+W7[3]*X[3]+W7[4]*X[4]+W7[5]*X[5]+W7[6]*X[6];
            break;
        default:
            s = W7[0]*X[7]+W7[1]*X[8]+W7[2]*X[9]+W7[3]*X[10]+W7[4]*X[11]+W7[5]*X[12]
              + W7[0]*X[8]+W7[1]*X[9]+W7[2]*X[10]+W7[3]*X[11]+W7[4]*X[12]
              + W7[0]*X[9]+W7[1]*X[10]+W7[2]*X[11]+W7[3]*X[12];
            break;
        }
        const float v = fmaxf(fmaf(s, sbn6[nb][0], sbn6[nb][1]), 0.f);
        term[nb][tix][cl] = v * sws6[nb][cl];
    }

    // ---- main rounds (barrier-free; planes stable) ----
    {   // round 0: waves 0-3 -> r0, waves 4-7 -> r1
        const int rr = tid >> 8;
        const int w  = tid & 255;
        bool act; int pair, tile;
        if (rr == 0) { act = (w < 249); pair = w / 83; tile = w % 83; }
        else         { act = (w < 252); pair = w / 84; tile = 83 + w % 84; }
        ROUND_BODY(act, rr, pair, tile)
    }
    {   // round 1: waves 0-3 -> r2
        const bool act = (tid < 249);
        const int pair = tid / 83;
        const int tile = 167 + tid % 83;
        ROUND_BODY(act, 2, pair, tile)
    }
    __syncthreads();   // S3: psum atomics + term complete

    // ---- write partials ----
    if (tid < MNB_) hpP[(size_t)(b*2 + half)*MNB_ + tid] = psum[tid];
    if (tid >= 64 && tid < 100) {
        const int k = tid - 64;                   // nb*6 + tix
        const int nb = k / 6, tix = k % 6;
        float s = 0.f;
        for (int c = 0; c < CH_; ++c) s += term[nb][tix][c];
        corrP[(size_t)(b*2 + half)*36 + k] = s;
    }
}

// ---------------------------------------------------------------------------
// Stage 2: combine halves + fold specials, gate (softmax/top-3), experts +
// EBN + ReLU + mix, FC + log_softmax. One block (64 thr) per batch element.
// ---------------------------------------------------------------------------
__global__ __launch_bounds__(64) void fb_stage2(
    const float* __restrict__ hpP, const float* __restrict__ corrP,
    const float* __restrict__ gate_w, const float* __restrict__ gate_b,
    const float* __restrict__ exp_w,  const float* __restrict__ exp_b,
    const float* __restrict__ ebn_g,  const float* __restrict__ ebn_b,
    const float* __restrict__ ebn_m,  const float* __restrict__ ebn_v,
    const float* __restrict__ fc_w,   const float* __restrict__ fc_b,
    float* __restrict__ feats_out, float* __restrict__ logp_out)
{
    const int b   = blockIdx.x;
    const int tid = threadIdx.x;

    __shared__ float hsum[MNB_];
    __shared__ float corr2[36];
    __shared__ float gms[NB_];
    __shared__ float lg[MNB_];
    __shared__ float gsh[E_];
    __shared__ float hps[MNB_];
    __shared__ float fsh[FEAT_];
    __shared__ float lo[NC_];

    if (tid < MNB_) hsum[tid] = hpP[(size_t)b*2*MNB_ + tid]
                              + hpP[(size_t)(b*2+1)*MNB_ + tid];
    if (tid >= 48 && tid < 84) {
        const int k = tid - 48;
        corr2[k] = corrP[(size_t)b*2*36 + k] + corrP[(size_t)(b*2+1)*36 + k];
    }
    __syncthreads();
    if (tid < NB_) {   // fold exact specials into their pooling windows
        hsum[tid*TP_ + 0] += corr2[tid*6 + 0];                    // t=0
        hsum[tid*TP_ + 2] += corr2[tid*6 + 1] + corr2[tid*6 + 2]; // 332,333
        hsum[tid*TP_ + 5] += corr2[tid*6 + 3] + corr2[tid*6 + 4]; // 666,667
        hsum[tid*TP_ + 7] += corr2[tid*6 + 5];                    // t=999
    }
    __syncthreads();
    if (tid < MNB_) hps[tid] = hsum[tid] * (1.f / POOL_);
    if (tid < NB_) {
        float s = 0.f;
        for (int p = 0; p < TP_; ++p) s += hsum[tid*TP_ + p];
        gms[tid] = s * (1.f / T_);
    }
    __syncthreads();

    if (tid < MNB_) {
        float s = gate_b[tid];
        for (int c = 0; c < NB_; ++c) s += gms[c] * gate_w[tid*NB_ + c];
        lg[tid] = s;
    }
    __syncthreads();
    if (tid == 0) {
        float mx = lg[0];
        for (int i = 1; i < MNB_; ++i) mx = fmaxf(mx, lg[i]);
        for (int i = 0; i < MNB_; ++i) lg[i] = expf(lg[i] - mx);
        int i1 = 0, i2 = -1, i3 = -1;
        float b1 = -1.f, b2 = -1.f, b3 = -1.f;
        for (int i = 0; i < MNB_; ++i) if (lg[i] > b1) { b1 = lg[i]; i1 = i; }
        for (int i = 0; i < MNB_; ++i) if (i != i1 && lg[i] > b2) { b2 = lg[i]; i2 = i; }
        for (int i = 0; i < MNB_; ++i) if (i != i1 && i != i2 && lg[i] > b3) { b3 = lg[i]; i3 = i; }
        const float s3 = lg[i1] + lg[i2] + lg[i3];
        for (int jj = 0; jj < E_; ++jj) gsh[jj] = 0.f;
        if (i1 < E_) gsh[i1] = lg[i1] / s3;
        if (i2 < E_) gsh[i2] = lg[i2] / s3;
        if (i3 < E_) gsh[i3] = lg[i3] / s3;
    }
    __syncthreads();

    #pragma unroll
    for (int rrr = 0; rrr < FEAT_/64; ++rrr) {
        const int idx = tid + rrr*64;       // 0..383
        const int o = idx >> 3, p = idx & 7;
        float outv = 0.f;
        #pragma unroll
        for (int e = 0; e < E_; ++e) {
            const int eo = e*MNB_ + o;
            float acc = exp_b[eo];
            #pragma unroll
            for (int c = 0; c < NB_; ++c)
                acc += hps[c*TP_ + p] * exp_w[eo*NB_ + c];
            const float esc = ebn_g[eo] * rsqrtf(ebn_v[eo] + 1e-5f);
            float v = fmaf(acc - ebn_m[eo], esc, ebn_b[eo]);
            v = fmaxf(v, 0.f);
            outv += gsh[e] * v;
        }
        fsh[idx] = outv;
        feats_out[b*FEAT_ + idx] = outv;
    }
    __syncthreads();

    if (tid < NC_) {
        float s = fc_b[tid];
        for (int i = 0; i < FEAT_; ++i) s += fsh[i] * fc_w[tid*FEAT_ + i];
        lo[tid] = s;
    }
    __syncthreads();
    if (tid == 0) {
        float mx = lo[0];
        for (int k = 1; k < NC_; ++k) mx = fmaxf(mx, lo[k]);
        float Z = 0.f;
        for (int k = 0; k < NC_; ++k) Z += expf(lo[k] - mx);
        const float lse = mx + logf(Z);
        for (int k = 0; k < NC_; ++k) logp_out[b*NC_ + k] = lo[k] - lse;
    }
}

extern "C" void kernel_launch(void* const* d_in, const int* in_sizes, int n_in,
                              void* d_out, int out_size, void* d_ws, size_t ws_size,
                              hipStream_t stream) {
    const float* x       = (const float*)d_in[0];
    const float* fir     = (const float*)d_in[1];
    const float* w3      = (const float*)d_in[2];
    const float* w5      = (const float*)d_in[3];
    const float* w7      = (const float*)d_in[4];
    const float* bn1_g   = (const float*)d_in[5];
    const float* bn1_b   = (const float*)d_in[6];
    const float* bn1_m   = (const float*)d_in[7];
    const float* bn1_v   = (const float*)d_in[8];
    const float* sconv_w = (const float*)d_in[9];
    const float* gate_w  = (const float*)d_in[10];
    const float* gate_b  = (const float*)d_in[11];
    const float* exp_w   = (const float*)d_in[12];
    const float* exp_b   = (const float*)d_in[13];
    const float* ebn_g   = (const float*)d_in[14];
    const float* ebn_b   = (const float*)d_in[15];
    const float* ebn_m   = (const float*)d_in[16];
    const float* ebn_v   = (const float*)d_in[17];
    const float* fc_w    = (const float*)d_in[18];
    const float* fc_b    = (const float*)d_in[19];

    float* out       = (float*)d_out;
    float* feats_out = out;                     // (256, 384)
    float* logp_out  = out + B_ * FEAT_;        // (256, 9)

    float* hpP   = (float*)d_ws;                // (256*2, 48) pooled partials
    float* corrP = hpP + B_ * 2 * MNB_;         // (256*2, 36) corr partials

    fb_stage1<<<2 * B_, NTH, 0, stream>>>(x, fir, w3, w5, w7,
                                          bn1_g, bn1_b, bn1_m, bn1_v,
                                          sconv_w, hpP, corrP);
    fb_stage2<<<B_, 64, 0, stream>>>(hpP, corrP, gate_w, gate_b,
                                     exp_w, exp_b, ebn_g, ebn_b, ebn_m, ebn_v,
                                     fc_w, fc_b, feats_out, logp_out);
}

// Round 13
// 88.268 us; speedup vs baseline: 1.9725x; 1.9725x over previous
//
#include <hip/hip_runtime.h>
#include <math.h>

#define B_    256
#define C_    22
#define T_    1000
#define NB_   6
#define E_    6
#define MNB_  48
#define POOL_ 125
#define TP_   8
#define NC_   9
#define FEAT_ 384   // MNB_*TP_

#define PQ_   352    // plane length; x[m] lives at (plane (m+24)%3, q (m+24)/3)
#define CH_   11     // channels per block (c-half)

// One pass of the unified (region-free) fused conv: window f[16] from a
// per-lane LDS base, shifted taps ck2[k][0..12] (zero-padded).
#define PASS(OFF, KK)                                                        \
    {                                                                        \
        float f[16];                                                         \
        const float4* pb = (const float4*)(base + (OFF));                    \
        *(float4*)&f[0]  = pb[0]; *(float4*)&f[4]  = pb[1];                  \
        *(float4*)&f[8]  = pb[2]; *(float4*)&f[12] = pb[3];                  \
        _Pragma("unroll")                                                    \
        for (int u = 0; u < 13; ++u) {                                       \
            const float ca = ckA2[KK][u];                                    \
            const float cb = ckB2[KK][u];                                    \
            sa0 = fmaf(ca, f[u    ], sa0);                                   \
            sa1 = fmaf(ca, f[u + 1], sa1);                                   \
            sa2 = fmaf(ca, f[u + 2], sa2);                                   \
            sa3 = fmaf(ca, f[u + 3], sa3);                                   \
            sb0 = fmaf(cb, f[u    ], sb0);                                   \
            sb1 = fmaf(cb, f[u + 1], sb1);                                   \
            sb2 = fmaf(cb, f[u + 2], sb2);                                   \
            sb3 = fmaf(cb, f[u + 3], sb3);                                   \
        }                                                                    \
    }

// ---------------------------------------------------------------------------
// Stage 1 (R13): grid = 3 pairs x 256 b x 2 halves (pair-major so same-x
// blocks share an XCD L2). 256 threads, __launch_bounds__(256,2) — the ONE
// config proven to give VGPR cap 128 with no spill (R3). Pair-blocked.
// Region divergence removed algebraically: shifted tap vectors ck2 make the
// inner loop identical for all lanes (per-lane LDS base offsets only).
// LDS ~50 KB -> 3 blocks/CU (12 waves). Outputs 16 pooled partials/block.
// ---------------------------------------------------------------------------
__global__ __launch_bounds__(256, 2) void fb_stage1(
    const float* __restrict__ x,
    const float* __restrict__ fir,
    const float* __restrict__ w3,
    const float* __restrict__ w5,
    const float* __restrict__ w7,
    const float* __restrict__ bn_g, const float* __restrict__ bn_b,
    const float* __restrict__ bn_m, const float* __restrict__ bn_v,
    const float* __restrict__ sconv_w,
    float* __restrict__ hpP)
{
    const int pair = blockIdx.x >> 9;          // 0..2
    const int rem  = blockIdx.x & 511;
    const int b    = rem >> 1;
    const int half = rem & 1;
    const int tid  = threadIdx.x;

    __shared__ __align__(16) float pl[CH_][3][PQ_];  // 46.5 KB; hrow aliases
    __shared__ float firs2[2][21];
    __shared__ float w3s2[2][3], w5s2[2][5], w7s2[2][7];
    __shared__ float sws2[2][CH_];
    __shared__ float sbn2[2][2];
    __shared__ float ckl2[3][2][3][13];  // [region][local nb][pass][u]
    __shared__ float xbv[2][CH_][13];    // xb(0..6), xb(994..999)
    __shared__ float term[2][6][CH_];
    __shared__ float corr[2][6];

    float (*hrow)[T_] = (float (*)[T_])pl;   // alias: valid after S3

    const float* xbase = x + (size_t)b * (C_ * T_) + half * (CH_ * T_);

    // ---- weights to LDS ----
    if (tid < 42)                     { int ln=tid/21, i=tid%21; firs2[ln][i] = fir[(pair*2+ln)*21 + i]; }
    else if (tid >= 64  && tid < 70)  { int k=tid-64;  w3s2[k/3][k%3] = w3[(pair*2 + k/3)*3 + k%3]; }
    else if (tid >= 96  && tid < 106) { int k=tid-96;  w5s2[k/5][k%5] = w5[(pair*2 + k/5)*5 + k%5]; }
    else if (tid >= 128 && tid < 142) { int k=tid-128; w7s2[k/7][k%7] = w7[(pair*2 + k/7)*7 + k%7]; }
    else if (tid >= 160 && tid < 182) { int k=tid-160; sws2[k/CH_][k%CH_] = sconv_w[(pair*2 + k/CH_)*C_ + half*CH_ + k%CH_]; }
    else if (tid >= 192 && tid < 194) {
        const int ln = tid - 192, nb = pair*2 + ln;
        float sc = bn_g[nb] * rsqrtf(bn_v[nb] + 1e-5f);
        sbn2[ln][0] = sc * (1.f/3.f);        // folds the /3 of the triple-mean
        sbn2[ln][1] = bn_b[nb] - bn_m[nb] * sc;
    }

    // ---- stage this half's 11 channels in plane order ----
    #pragma unroll
    for (int k = 0; k < 12; ++k) {
        const int idx = tid + (k << 8);           // 0..3071
        if (idx < CH_ * 264) {                    // 2904
            const int cl = idx / 264, r2 = idx % 264;
            const int p  = r2 / 88,  q0 = (r2 % 88) * 4;
            const float* xr = xbase + cl * T_;
            float v[4];
            #pragma unroll
            for (int i = 0; i < 4; ++i) {
                const int m  = 3 * (q0 + i) + p - 24;
                const int mc = m < 0 ? 0 : (m > 999 ? 999 : m);
                const float val = xr[mc];
                v[i] = ((unsigned)m < 1000u) ? val : 0.f;
            }
            *(float4*)&pl[cl][p][q0] = make_float4(v[0], v[1], v[2], v[3]);
        }
    }
    __syncthreads();   // S1: planes + weights visible

    // ---- build shifted tap table ck2 (234 items, one per thread) ----
    if (tid < 234) {
        const int rr2 = tid / 78, r78 = tid % 78;
        const int ln  = r78 / 39, r39 = r78 % 39;
        const int k   = r39 / 13, u   = r39 % 13;
        const int IDX0[3][3] = {{3,0,0},{2,2,3},{1,1,1}};
        const int jj = k + 3*u - 3*IDX0[rr2][k];
        float s = 0.f;
        if (jj >= 0 && jj < 29) {
            const float* wk = (rr2 == 0) ? w3s2[ln] : (rr2 == 1 ? w5s2[ln] : w7s2[ln]);
            const int K = (rr2 == 0) ? 3 : (rr2 == 1 ? 5 : 7), pk = K >> 1;
            #pragma unroll
            for (int oi = 0; oi < 9; ++oi) {
                const int o = oi - 3;
                float we = 0.f;
                for (int kk = 0; kk < 7; ++kk) {
                    if (kk < K) {
                        const int jx = o + pk - kk;
                        if (jx >= 0 && jx < 3) we += wk[kk];
                    }
                }
                const int i = jj - oi;
                if (i >= 0 && i < 21) s = fmaf(we, firs2[ln][i], s);
            }
        }
        ckl2[rr2][ln][k][u] = s;
    }
    // ---- phaseB: boundary FIR dots (286 items) ----
    for (int idx = tid; idx < 2 * CH_ * 13; idx += 256) {
        const int ln = idx / (CH_ * 13), r143 = idx % (CH_ * 13);
        const int cl = r143 / 13, pos = r143 % 13;
        const int m  = (pos < 7) ? pos : (987 + pos);   // 0..6, 994..999
        int mm = m + 14;                                // (m-10)+24
        int q  = mm / 3, p = mm - 3 * q;
        float s = 0.f;
        #pragma unroll
        for (int i = 0; i < 21; ++i) {
            s = fmaf(firs2[ln][i], pl[cl][p][q], s);
            ++p; if (p == 3) { p = 0; ++q; }
        }
        xbv[ln][cl][pos] = s;
    }
    __syncthreads();   // S2: ckl2 + xbv visible

    // ---- phaseC: partial special outputs (132 items) ----
    if (tid < 132) {
        const int ln  = tid / 66, r66 = tid % 66;
        const int tix = r66 / CH_, cl = r66 % CH_;
        const float* X  = xbv[ln][cl];  // X[0..6]=xb(0..6), X[7..12]=xb(994..999)
        const float* W3 = w3s2[ln];
        const float* W5 = w5s2[ln];
        const float* W7 = w7s2[ln];
        float s;
        switch (tix) {
        case 0:
            s = W3[1]*X[0]+W3[2]*X[1]
              + W3[0]*X[0]+W3[1]*X[1]+W3[2]*X[2]
              + W3[0]*X[1]+W3[1]*X[2]+W3[2]*X[3];
            break;
        case 1:
            s = W3[0]*X[8]+W3[1]*X[9]+W3[2]*X[10]
              + W3[0]*X[9]+W3[1]*X[10]+W3[2]*X[11]
              + W3[0]*X[10]+W3[1]*X[11]+W3[2]*X[12];
            break;
        case 2:
            s = W3[0]*X[11]+W3[1]*X[12]
              + W5[2]*X[0]+W5[3]*X[1]+W5[4]*X[2]
              + W5[1]*X[0]+W5[2]*X[1]+W5[3]*X[2]+W5[4]*X[3];
            break;
        case 3:
            s = W5[0]*X[9]+W5[1]*X[10]+W5[2]*X[11]+W5[3]*X[12]
              + W5[0]*X[10]+W5[1]*X[11]+W5[2]*X[12]
              + W7[3]*X[0]+W7[4]*X[1]+W7[5]*X[2]+W7[6]*X[3];
            break;
        case 4:
            s = W7[2]*X[0]+W7[3]*X[1]+W7[4]*X[2]+W7[5]*X[3]+W7[6]*X[4]
              + W7[1]*X[0]+W7[2]*X[1]+W7[3]*X[2]+W7[4]*X[3]+W7[5]*X[4]+W7[6]*X[5]
              + W7[0]*X[0]+W7[1]*X[1]+W7[2]*X[2]+W7[3]*X[3]+W7[4]*X[4]+W7[5]*X[5]+W7[6]*X[6];
            break;
        default:
            s = W7[0]*X[7]+W7[1]*X[8]+W7[2]*X[9]+W7[3]*X[10]+W7[4]*X[11]+W7[5]*X[12]
              + W7[0]*X[8]+W7[1]*X[9]+W7[2]*X[10]+W7[3]*X[11]+W7[4]*X[12]
              + W7[0]*X[9]+W7[1]*X[10]+W7[2]*X[11]+W7[3]*X[12];
            break;
        }
        const float v = fmaxf(fmaf(s, sbn2[ln][0], sbn2[ln][1]), 0.f);
        term[ln][tix][cl] = v * sws2[ln][cl];
    }

    // ---- per-thread setup: gather shifted taps + per-lane base offsets ----
    const bool act = (tid < 250);
    const int  rr  = (tid <= 82) ? 0 : (tid <= 166) ? 1 : 2;

    float ckA2[3][13], ckB2[3][13];
    int off0 = 0, off1 = 0, off2 = 0;
    float scA = 0.f, biA = 0.f, scB = 0.f, biB = 0.f;
    if (act) {
        #pragma unroll
        for (int k = 0; k < 3; ++k)
            #pragma unroll
            for (int u = 0; u < 13; ++u) {
                ckA2[k][u] = ckl2[rr][0][k][u];
                ckB2[k][u] = ckl2[rr][1][k][u];
            }
        const int PLN[3][3]  = {{2,0,1},{1,2,0},{0,1,2}};
        const int AOFF[3][3] = {{0,4,4},{-332,-332,-332},{-664,-664,-664}};
        off0 = PLN[rr][0]*PQ_ + 4*tid + AOFF[rr][0];
        off1 = PLN[rr][1]*PQ_ + 4*tid + AOFF[rr][1];
        off2 = PLN[rr][2]*PQ_ + 4*tid + AOFF[rr][2];
        scA = sbn2[0][0]; biA = sbn2[0][1];
        scB = sbn2[1][0]; biB = sbn2[1][1];
    }

    // ---- main loop: uniform, barrier-free ----
    float aA0=0.f, aA1=0.f, aA2=0.f, aA3=0.f;
    float aB0=0.f, aB1=0.f, aB2=0.f, aB3=0.f;
    if (act) {
        #pragma unroll 1
        for (int c = 0; c < CH_; ++c) {
            const float* base = &pl[c][0][0];
            float sa0=0.f, sa1=0.f, sa2=0.f, sa3=0.f;
            float sb0=0.f, sb1=0.f, sb2=0.f, sb3=0.f;
            PASS(off0, 0)
            PASS(off1, 1)
            PASS(off2, 2)
            const float swA = sws2[0][c], swB = sws2[1][c];
            aA0 += fmaxf(fmaf(sa0, scA, biA), 0.f) * swA;
            aA1 += fmaxf(fmaf(sa1, scA, biA), 0.f) * swA;
            aA2 += fmaxf(fmaf(sa2, scA, biA), 0.f) * swA;
            aA3 += fmaxf(fmaf(sa3, scA, biA), 0.f) * swA;
            aB0 += fmaxf(fmaf(sb0, scB, biB), 0.f) * swB;
            aB1 += fmaxf(fmaf(sb1, scB, biB), 0.f) * swB;
            aB2 += fmaxf(fmaf(sb2, scB, biB), 0.f) * swB;
            aB3 += fmaxf(fmaf(sb3, scB, biB), 0.f) * swB;
        }
    }
    __syncthreads();   // S3: all pl reads done -> hrow alias safe

    if (act) {
        *(float4*)&hrow[0][4*tid] = make_float4(aA0, aA1, aA2, aA3);
        *(float4*)&hrow[1][4*tid] = make_float4(aB0, aB1, aB2, aB3);
    }
    if (tid < 12) {    // corr reduce over this half's channels
        const int ln = tid / 6, tix = tid % 6;
        float s = 0.f;
        for (int c = 0; c < CH_; ++c) s += term[ln][tix][c];
        corr[ln][tix] = s;
    }
    __syncthreads();
    if (tid < 12) {    // substitute exact special outputs
        const int ln = tid / 6, tix = tid % 6;
        const int t = (tix == 0) ? 0 :
                      (tix <= 2) ? (331 + tix) :        // 332, 333
                      (tix <= 4) ? (663 + tix) : 999;   // 666, 667
        hrow[ln][t] = corr[ln][tix];
    }
    __syncthreads();

    // ---- pooling: 16 windows x 8 lanes -> hpP ----
    if (tid < 128) {
        const int w = tid >> 3, jj = tid & 7;
        const int ln = w >> 3, p = w & 7;
        float s = 0.f;
        for (int k = jj; k < POOL_; k += 8) s += hrow[ln][p*POOL_ + k];
        s += __shfl_down(s, 4, 8);
        s += __shfl_down(s, 2, 8);
        s += __shfl_down(s, 1, 8);
        if (jj == 0) hpP[(size_t)blockIdx.x * 16 + w] = s;   // window SUM
    }
}

// ---------------------------------------------------------------------------
// Stage 2: merge 6 partial blocks (3 pairs x 2 halves), gate (softmax/top-3),
// experts + EBN + ReLU + mix, FC + log_softmax. One 64-thread block per b.
// ---------------------------------------------------------------------------
__global__ __launch_bounds__(64) void fb_stage2(
    const float* __restrict__ hpP,
    const float* __restrict__ gate_w, const float* __restrict__ gate_b,
    const float* __restrict__ exp_w,  const float* __restrict__ exp_b,
    const float* __restrict__ ebn_g,  const float* __restrict__ ebn_b,
    const float* __restrict__ ebn_m,  const float* __restrict__ ebn_v,
    const float* __restrict__ fc_w,   const float* __restrict__ fc_b,
    float* __restrict__ feats_out, float* __restrict__ logp_out)
{
    const int b   = blockIdx.x;
    const int tid = threadIdx.x;

    __shared__ float hsum[MNB_];
    __shared__ float hps[MNB_];
    __shared__ float gms[NB_];
    __shared__ float lg[MNB_];
    __shared__ float gsh[E_];
    __shared__ float fsh[FEAT_];
    __shared__ float lo[NC_];

    if (tid < MNB_) {
        const int nb = tid >> 3, p = tid & 7;
        const int pr = nb >> 1, ln = nb & 1;
        const size_t base0 = ((size_t)(pr << 9) + (b << 1)) * 16 + ln*8 + p;
        const float s = hpP[base0] + hpP[base0 + 16];
        hsum[tid] = s;
        hps[tid]  = s * (1.f / POOL_);
    }
    __syncthreads();
    if (tid < NB_) {
        float s = 0.f;
        for (int p = 0; p < TP_; ++p) s += hsum[tid*TP_ + p];
        gms[tid] = s * (1.f / T_);
    }
    __syncthreads();

    if (tid < MNB_) {
        float s = gate_b[tid];
        for (int c = 0; c < NB_; ++c) s += gms[c] * gate_w[tid*NB_ + c];
        lg[tid] = s;
    }
    __syncthreads();
    if (tid == 0) {
        float mx = lg[0];
        for (int i = 1; i < MNB_; ++i) mx = fmaxf(mx, lg[i]);
        for (int i = 0; i < MNB_; ++i) lg[i] = expf(lg[i] - mx);
        int i1 = 0, i2 = -1, i3 = -1;
        float b1 = -1.f, b2 = -1.f, b3 = -1.f;
        for (int i = 0; i < MNB_; ++i) if (lg[i] > b1) { b1 = lg[i]; i1 = i; }
        for (int i = 0; i < MNB_; ++i) if (i != i1 && lg[i] > b2) { b2 = lg[i]; i2 = i; }
        for (int i = 0; i < MNB_; ++i) if (i != i1 && i != i2 && lg[i] > b3) { b3 = lg[i]; i3 = i; }
        const float s3 = lg[i1] + lg[i2] + lg[i3];
        for (int jj = 0; jj < E_; ++jj) gsh[jj] = 0.f;
        if (i1 < E_) gsh[i1] = lg[i1] / s3;
        if (i2 < E_) gsh[i2] = lg[i2] / s3;
        if (i3 < E_) gsh[i3] = lg[i3] / s3;
    }
    __syncthreads();

    #pragma unroll
    for (int rrr = 0; rrr < FEAT_/64; ++rrr) {
        const int idx = tid + rrr*64;       // 0..383
        const int o = idx >> 3, p = idx & 7;
        float outv = 0.f;
        #pragma unroll
        for (int e = 0; e < E_; ++e) {
            const int eo = e*MNB_ + o;
            float acc = exp_b[eo];
            #pragma unroll
            for (int c = 0; c < NB_; ++c)
                acc += hps[c*TP_ + p] * exp_w[eo*NB_ + c];
            const float esc = ebn_g[eo] * rsqrtf(ebn_v[eo] + 1e-5f);
            float v = fmaf(acc - ebn_m[eo], esc, ebn_b[eo]);
            v = fmaxf(v, 0.f);
            outv += gsh[e] * v;
        }
        fsh[idx] = outv;
        feats_out[b*FEAT_ + idx] = outv;
    }
    __syncthreads();

    if (tid < NC_) {
        float s = fc_b[tid];
        for (int i = 0; i < FEAT_; ++i) s += fsh[i] * fc_w[tid*FEAT_ + i];
        lo[tid] = s;
    }
    __syncthreads();
    if (tid == 0) {
        float mx = lo[0];
        for (int k = 1; k < NC_; ++k) mx = fmaxf(mx, lo[k]);
        float Z = 0.f;
        for (int k = 0; k < NC_; ++k) Z += expf(lo[k] - mx);
        const float lse = mx + logf(Z);
        for (int k = 0; k < NC_; ++k) logp_out[b*NC_ + k] = lo[k] - lse;
    }
}

extern "C" void kernel_launch(void* const* d_in, const int* in_sizes, int n_in,
                              void* d_out, int out_size, void* d_ws, size_t ws_size,
                              hipStream_t stream) {
    const float* x       = (const float*)d_in[0];
    const float* fir     = (const float*)d_in[1];
    const float* w3      = (const float*)d_in[2];
    const float* w5      = (const float*)d_in[3];
    const float* w7      = (const float*)d_in[4];
    const float* bn1_g   = (const float*)d_in[5];
    const float* bn1_b   = (const float*)d_in[6];
    const float* bn1_m   = (const float*)d_in[7];
    const float* bn1_v   = (const float*)d_in[8];
    const float* sconv_w = (const float*)d_in[9];
    const float* gate_w  = (const float*)d_in[10];
    const float* gate_b  = (const float*)d_in[11];
    const float* exp_w   = (const float*)d_in[12];
    const float* exp_b   = (const float*)d_in[13];
    const float* ebn_g   = (const float*)d_in[14];
    const float* ebn_b   = (const float*)d_in[15];
    const float* ebn_m   = (const float*)d_in[16];
    const float* ebn_v   = (const float*)d_in[17];
    const float* fc_w    = (const float*)d_in[18];
    const float* fc_b    = (const float*)d_in[19];

    float* out       = (float*)d_out;
    float* feats_out = out;                     // (256, 384)
    float* logp_out  = out + B_ * FEAT_;        // (256, 9)

    float* hpP = (float*)d_ws;                  // (1536, 16) pooled partial sums

    fb_stage1<<<3 * B_ * 2, 256, 0, stream>>>(x, fir, w3, w5, w7,
                                              bn1_g, bn1_b, bn1_m, bn1_v,
                                              sconv_w, hpP);
    fb_stage2<<<B_, 64, 0, stream>>>(hpP, gate_w, gate_b,
                                     exp_w, exp_b, ebn_g, ebn_b, ebn_m, ebn_v,
                                     fc_w, fc_b, feats_out, logp_out);
}

// Round 14
// 62.878 us; speedup vs baseline: 2.7689x; 1.4038x over previous
//
#include <hip/hip_runtime.h>
#include <math.h>

#define B_    256
#define C_    22
#define T_    1000
#define NB_   6
#define E_    6
#define MNB_  48
#define POOL_ 125
#define TP_   8
#define NC_   9
#define FEAT_ 384   // MNB_*TP_

#define PQ_   352    // plane length; x[m] lives at (plane (m+24)%3, q (m+24)/3)
#define NTH   768
#define CH_   11     // channels per staging half

// One pass of the uniform fused conv for ONE nb: window f[16] from per-lane
// LDS base+offset, shifted taps ck2[KK][0..12] (zero-padded).
#define PASS(OFF, KK)                                                        \
    {                                                                        \
        float f[16];                                                         \
        const float4* pb = (const float4*)(base + (OFF));                    \
        *(float4*)&f[0]  = pb[0]; *(float4*)&f[4]  = pb[1];                  \
        *(float4*)&f[8]  = pb[2]; *(float4*)&f[12] = pb[3];                  \
        _Pragma("unroll")                                                    \
        for (int u = 0; u < 13; ++u) {                                       \
            const float cj = ck2[KK][u];                                     \
            s0 = fmaf(cj, f[u    ], s0);                                     \
            s1 = fmaf(cj, f[u + 1], s1);                                     \
            s2 = fmaf(cj, f[u + 2], s2);                                     \
            s3 = fmaf(cj, f[u + 3], s3);                                     \
        }                                                                    \
    }

// Main loop over one channel-half for one nb: gathers taps, accumulates
// BN+ReLU+sconv into A0..A3 (named scalars passed by reference).
#define RUN_NB(NBV, A0, A1, A2, A3)                                          \
    {                                                                        \
        const int nbL = (NBV);                                               \
        float ck2[3][13];                                                    \
        _Pragma("unroll")                                                    \
        for (int k = 0; k < 3; ++k)                                          \
            _Pragma("unroll")                                                \
            for (int u = 0; u < 13; ++u) ck2[k][u] = ckl2[rr][nbL][k][u];    \
        const float sc3 = sbn6[nbL][0], bi = sbn6[nbL][1];                   \
        _Pragma("unroll 1")                                                  \
        for (int c = 0; c < CH_; ++c) {                                      \
            const float* base = &pl[c][0][0];                                \
            float s0 = 0.f, s1 = 0.f, s2 = 0.f, s3 = 0.f;                    \
            PASS(off0, 0)                                                    \
            PASS(off1, 1)                                                    \
            PASS(off2, 2)                                                    \
            const float sw = sws6[nbL][h * CH_ + c];                         \
            A0 += fmaxf(fmaf(s0, sc3, bi), 0.f) * sw;                        \
            A1 += fmaxf(fmaf(s1, sc3, bi), 0.f) * sw;                        \
            A2 += fmaxf(fmaf(s2, sc3, bi), 0.f) * sw;                        \
            A3 += fmaxf(fmaf(s3, sc3, bi), 0.f) * sw;                        \
        }                                                                    \
    }

// ---------------------------------------------------------------------------
// R14: single fused kernel (R8 shell) + R13 uniform shifted taps, single-nb
// per thread (~70 VGPR demand <= compiler's 84 -> no spill, no LDS remat).
// grid 256 (one block per b), 768 threads; 1500 (nb,tile) units in 2 rounds
// of 750; channel-halved staging (11-ch planes, 46.5 KB); accs carried in
// regs across halves; hrow aliases planes; stage2 inline.
// ---------------------------------------------------------------------------
__global__ __launch_bounds__(NTH) void fb_fused(
    const float* __restrict__ x,
    const float* __restrict__ fir,
    const float* __restrict__ w3,
    const float* __restrict__ w5,
    const float* __restrict__ w7,
    const float* __restrict__ bn_g, const float* __restrict__ bn_b,
    const float* __restrict__ bn_m, const float* __restrict__ bn_v,
    const float* __restrict__ sconv_w,
    const float* __restrict__ gate_w, const float* __restrict__ gate_b,
    const float* __restrict__ exp_w,  const float* __restrict__ exp_b,
    const float* __restrict__ ebn_g,  const float* __restrict__ ebn_b,
    const float* __restrict__ ebn_m,  const float* __restrict__ ebn_v,
    const float* __restrict__ fc_w,   const float* __restrict__ fc_b,
    float* __restrict__ feats_out, float* __restrict__ logp_out)
{
    const int b   = blockIdx.x;
    const int tid = threadIdx.x;

    __shared__ __align__(16) float pl[CH_][3][PQ_];  // 46.5 KB; hrow aliases
    __shared__ float firs6[NB_][21];
    __shared__ float w3s6[NB_][3], w5s6[NB_][5], w7s6[NB_][7];
    __shared__ float sws6[NB_][C_];
    __shared__ float sbn6[NB_][2];
    __shared__ float ckl2[3][NB_][3][13];  // shifted taps [rgn][nb][pass][u]
    __shared__ float xbv[NB_][CH_][13];    // xb(0..6), xb(994..999) per half
    __shared__ float term[NB_][6][C_];
    __shared__ float corr[NB_][6];
    __shared__ float psum[MNB_];
    __shared__ float hpl[MNB_];
    __shared__ float gms[NB_];
    __shared__ float lg[MNB_];
    __shared__ float gsh[E_];
    __shared__ float fsh[FEAT_];
    __shared__ float fpart[NC_][8];
    __shared__ float lo[NC_];

    float (*hrow)[T_] = (float (*)[T_])pl;   // alias: valid after final S3

    const float* xbase = x + (size_t)b * (C_ * T_);

    // ---- weights to LDS ----
    if (tid < 126)                      { int nb=tid/21; firs6[nb][tid%21] = fir[tid]; }
    else if (tid >= 128 && tid < 146)   { int k=tid-128; w3s6[k/3][k%3] = w3[k]; }
    else if (tid >= 160 && tid < 190)   { int k=tid-160; w5s6[k/5][k%5] = w5[k]; }
    else if (tid >= 192 && tid < 234)   { int k=tid-192; w7s6[k/7][k%7] = w7[k]; }
    else if (tid >= 256 && tid < 388)   { int k=tid-256; sws6[k/C_][k%C_] = sconv_w[k]; }
    else if (tid >= 400 && tid < 406) {
        const int nb = tid - 400;
        float sc = bn_g[nb] * rsqrtf(bn_v[nb] + 1e-5f);
        sbn6[nb][0] = sc * (1.f/3.f);        // folds the /3 of the triple-mean
        sbn6[nb][1] = bn_b[nb] - bn_m[nb] * sc;
    }

    // ---- per-thread unit mapping: 2 rounds x 750 units ----
    const bool act  = (tid < 750);
    const int  tile = act ? (tid % 250) : 0;
    const int  nbA  = act ? (tid / 250) : 0;       // round 0: nb 0..2
    const int  nbB  = nbA + 3;                     // round 1: nb 3..5
    const int  rr   = (tile <= 82) ? 0 : (tile <= 166) ? 1 : 2;

    const int PLN[3][3]  = {{2,0,1},{1,2,0},{0,1,2}};
    const int AOFF[3][3] = {{0,4,4},{-332,-332,-332},{-664,-664,-664}};
    const int off0 = PLN[rr][0]*PQ_ + 4*tile + AOFF[rr][0];
    const int off1 = PLN[rr][1]*PQ_ + 4*tile + AOFF[rr][1];
    const int off2 = PLN[rr][2]*PQ_ + 4*tile + AOFF[rr][2];

    float aA0=0.f, aA1=0.f, aA2=0.f, aA3=0.f;   // round-0 accs
    float aB0=0.f, aB1=0.f, aB2=0.f, aB3=0.f;   // round-1 accs

    #pragma unroll 1
    for (int h = 0; h < 2; ++h) {
        // ---- stage half h: 11 channels in plane order ----
        #pragma unroll
        for (int k = 0; k < 4; ++k) {
            const int idx = tid + k * NTH;            // 0..3071
            if (idx < CH_ * 264) {                    // 2904
                const int cl = idx / 264, r2 = idx % 264;
                const int p  = r2 / 88,  q0 = (r2 % 88) * 4;
                const float* xr = xbase + (h * CH_ + cl) * T_;
                float v[4];
                #pragma unroll
                for (int i = 0; i < 4; ++i) {
                    const int m  = 3 * (q0 + i) + p - 24;
                    const int mc = m < 0 ? 0 : (m > 999 ? 999 : m);
                    const float val = xr[mc];
                    v[i] = ((unsigned)m < 1000u) ? val : 0.f;
                }
                *(float4*)&pl[cl][p][q0] = make_float4(v[0], v[1], v[2], v[3]);
            }
        }
        __syncthreads();   // S1: planes (+ h==0: weights) visible

        // ---- (h==0) build shifted tap table: 702 items ----
        if (h == 0 && tid < 702) {
            const int rr2 = tid / 234, r234 = tid % 234;
            const int nb  = r234 / 39, r39 = r234 % 39;
            const int k   = r39 / 13,  u   = r39 % 13;
            const int IDX0[3][3] = {{3,0,0},{2,2,3},{1,1,1}};
            const int jj = k + 3*u - 3*IDX0[rr2][k];
            float s = 0.f;
            if (jj >= 0 && jj < 29) {
                const float* wk = (rr2 == 0) ? w3s6[nb] : (rr2 == 1 ? w5s6[nb] : w7s6[nb]);
                const int K = (rr2 == 0) ? 3 : (rr2 == 1 ? 5 : 7), pk = K >> 1;
                #pragma unroll
                for (int oi = 0; oi < 9; ++oi) {
                    const int o = oi - 3;
                    float we = 0.f;
                    for (int kk = 0; kk < 7; ++kk) {
                        if (kk < K) {
                            const int jx = o + pk - kk;
                            if (jx >= 0 && jx < 3) we += wk[kk];
                        }
                    }
                    const int i = jj - oi;
                    if (i >= 0 && i < 21) s = fmaf(we, firs6[nb][i], s);
                }
            }
            ckl2[rr2][nb][k][u] = s;
        }
        // ---- phaseB: boundary FIR dots, 858 items ----
        for (int idx = tid; idx < NB_ * CH_ * 13; idx += NTH) {
            const int nb = idx / (CH_ * 13), r143 = idx % (CH_ * 13);
            const int cl = r143 / 13, pos = r143 % 13;
            const int m  = (pos < 7) ? pos : (987 + pos);   // 0..6, 994..999
            int mm = m + 14;                                // (m-10)+24
            int q  = mm / 3, p = mm - 3 * q;
            float s = 0.f;
            #pragma unroll
            for (int i = 0; i < 21; ++i) {
                s = fmaf(firs6[nb][i], pl[cl][p][q], s);
                ++p; if (p == 3) { p = 0; ++q; }
            }
            xbv[nb][cl][pos] = s;
        }
        __syncthreads();   // S2: ckl2 + xbv visible

        // ---- phaseC: partial special outputs (this half), 396 items ----
        if (tid < NB_ * 6 * CH_) {
            const int nb  = tid / (6 * CH_), r66 = tid % (6 * CH_);
            const int tix = r66 / CH_, cl = r66 % CH_;
            const float* X  = xbv[nb][cl];  // X[0..6]=xb(0..6), X[7..12]=xb(994..999)
            const float* W3 = w3s6[nb];
            const float* W5 = w5s6[nb];
            const float* W7 = w7s6[nb];
            float s;
            switch (tix) {
            case 0:
                s = W3[1]*X[0]+W3[2]*X[1]
                  + W3[0]*X[0]+W3[1]*X[1]+W3[2]*X[2]
                  + W3[0]*X[1]+W3[1]*X[2]+W3[2]*X[3];
                break;
            case 1:
                s = W3[0]*X[8]+W3[1]*X[9]+W3[2]*X[10]
                  + W3[0]*X[9]+W3[1]*X[10]+W3[2]*X[11]
                  + W3[0]*X[10]+W3[1]*X[11]+W3[2]*X[12];
                break;
            case 2:
                s = W3[0]*X[11]+W3[1]*X[12]
                  + W5[2]*X[0]+W5[3]*X[1]+W5[4]*X[2]
                  + W5[1]*X[0]+W5[2]*X[1]+W5[3]*X[2]+W5[4]*X[3];
                break;
            case 3:
                s = W5[0]*X[9]+W5[1]*X[10]+W5[2]*X[11]+W5[3]*X[12]
                  + W5[0]*X[10]+W5[1]*X[11]+W5[2]*X[12]
                  + W7[3]*X[0]+W7[4]*X[1]+W7[5]*X[2]+W7[6]*X[3];
                break;
            case 4:
                s = W7[2]*X[0]+W7[3]*X[1]+W7[4]*X[2]+W7[5]*X[3]+W7[6]*X[4]
                  + W7[1]*X[0]+W7[2]*X[1]+W7[3]*X[2]+W7[4]*X[3]+W7[5]*X[4]+W7[6]*X[5]
                  + W7[0]*X[0]+W7[1]*X[1]+W7[2]*X[2]+W7[3]*X[3]+W7[4]*X[4]+W7[5]*X[5]+W7[6]*X[6];
                break;
            default:
                s = W7[0]*X[7]+W7[1]*X[8]+W7[2]*X[9]+W7[3]*X[10]+W7[4]*X[11]+W7[5]*X[12]
                  + W7[0]*X[8]+W7[1]*X[9]+W7[2]*X[10]+W7[3]*X[11]+W7[4]*X[12]
                  + W7[0]*X[9]+W7[1]*X[10]+W7[2]*X[11]+W7[3]*X[12];
                break;
            }
            const float v = fmaxf(fmaf(s, sbn6[nb][0], sbn6[nb][1]), 0.f);
            term[nb][tix][h * CH_ + cl] = v * sws6[nb][h * CH_ + cl];
        }

        // ---- main: 2 rounds, single-nb each (barrier-free) ----
        if (act) {
            RUN_NB(nbA, aA0, aA1, aA2, aA3)
            RUN_NB(nbB, aB0, aB1, aB2, aB3)
        }
        __syncthreads();   // S3: pl reads done; restage (h=0) / alias (h=1)
    }

    // ---- hrow writes (alias pl) + corr reduce ----
    if (act) {
        *(float4*)&hrow[nbA][4*tile] = make_float4(aA0, aA1, aA2, aA3);
        *(float4*)&hrow[nbB][4*tile] = make_float4(aB0, aB1, aB2, aB3);
    }
    if (tid >= 704 && tid < 740) {
        const int k = tid - 704;
        const int nb = k / 6, tix = k % 6;
        float s = 0.f;
        for (int c = 0; c < C_; ++c) s += term[nb][tix][c];
        corr[nb][tix] = s;
    }
    __syncthreads();
    if (tid < 36) {    // substitute exact special outputs
        const int nb = tid / 6, tix = tid % 6;
        const int t = (tix == 0) ? 0 :
                      (tix <= 2) ? (331 + tix) :        // 332, 333
                      (tix <= 4) ? (663 + tix) : 999;   // 666, 667
        hrow[nb][t] = corr[nb][tix];
    }
    __syncthreads();

    // ---- pooling: 48 windows x 8 lanes ----
    if (tid < 384) {
        const int w = tid >> 3, jj = tid & 7;
        const int nb = w >> 3, p = w & 7;
        float s = 0.f;
        for (int k = jj; k < POOL_; k += 8) s += hrow[nb][p*POOL_ + k];
        s += __shfl_down(s, 4, 8);
        s += __shfl_down(s, 2, 8);
        s += __shfl_down(s, 1, 8);
        if (jj == 0) { psum[w] = s; hpl[w] = s * (1.f / POOL_); }
    }
    __syncthreads();
    if (tid < NB_) {
        float s = 0.f;
        for (int p = 0; p < TP_; ++p) s += psum[tid*TP_ + p];
        gms[tid] = s * (1.f / T_);
    }
    __syncthreads();

    // ---- stage2: gate logits ----
    if (tid < MNB_) {
        float s = gate_b[tid];
        for (int c = 0; c < NB_; ++c) s += gms[c] * gate_w[tid*NB_ + c];
        lg[tid] = s;
    }
    __syncthreads();
    if (tid == 0) {
        float mx = lg[0];
        for (int i = 1; i < MNB_; ++i) mx = fmaxf(mx, lg[i]);
        for (int i = 0; i < MNB_; ++i) lg[i] = expf(lg[i] - mx);
        int i1 = 0, i2 = -1, i3 = -1;
        float b1 = -1.f, b2 = -1.f, b3 = -1.f;
        for (int i = 0; i < MNB_; ++i) if (lg[i] > b1) { b1 = lg[i]; i1 = i; }
        for (int i = 0; i < MNB_; ++i) if (i != i1 && lg[i] > b2) { b2 = lg[i]; i2 = i; }
        for (int i = 0; i < MNB_; ++i) if (i != i1 && i != i2 && lg[i] > b3) { b3 = lg[i]; i3 = i; }
        const float s3 = lg[i1] + lg[i2] + lg[i3];
        for (int jj = 0; jj < E_; ++jj) gsh[jj] = 0.f;
        if (i1 < E_) gsh[i1] = lg[i1] / s3;
        if (i2 < E_) gsh[i2] = lg[i2] / s3;
        if (i3 < E_) gsh[i3] = lg[i3] / s3;
    }
    __syncthreads();

    // ---- experts + EBN + ReLU + gate-mix -> feats ----
    if (tid < FEAT_) {
        const int o = tid >> 3, p = tid & 7;
        float outv = 0.f;
        #pragma unroll
        for (int e = 0; e < E_; ++e) {
            const int eo = e*MNB_ + o;
            float acc = exp_b[eo];
            #pragma unroll
            for (int c = 0; c < NB_; ++c)
                acc += hpl[c*TP_ + p] * exp_w[eo*NB_ + c];
            const float esc = ebn_g[eo] * rsqrtf(ebn_v[eo] + 1e-5f);
            float v = fmaf(acc - ebn_m[eo], esc, ebn_b[eo]);
            v = fmaxf(v, 0.f);
            outv += gsh[e] * v;
        }
        fsh[tid] = outv;
        feats_out[b*FEAT_ + tid] = outv;
    }
    __syncthreads();

    // ---- FC: 9 classes x 8 partials ----
    if (tid < NC_ * 8) {
        const int cls = tid >> 3, part = tid & 7;
        float s = 0.f;
        const float* wr = fc_w + cls*FEAT_ + part*48;
        const float* fr = fsh + part*48;
        for (int i = 0; i < 48; ++i) s = fmaf(fr[i], wr[i], s);
        fpart[cls][part] = s;
    }
    __syncthreads();
    if (tid < NC_) {
        float s = fc_b[tid];
        for (int p = 0; p < 8; ++p) s += fpart[tid][p];
        lo[tid] = s;
    }
    __syncthreads();
    if (tid == 0) {
        float mx = lo[0];
        for (int k = 1; k < NC_; ++k) mx = fmaxf(mx, lo[k]);
        float Z = 0.f;
        for (int k = 0; k < NC_; ++k) Z += expf(lo[k] - mx);
        const float lse = mx + logf(Z);
        for (int k = 0; k < NC_; ++k) logp_out[b*NC_ + k] = lo[k] - lse;
    }
}

extern "C" void kernel_launch(void* const* d_in, const int* in_sizes, int n_in,
                              void* d_out, int out_size, void* d_ws, size_t ws_size,
                              hipStream_t stream) {
    const float* x       = (const float*)d_in[0];
    const float* fir     = (const float*)d_in[1];
    const float* w3      = (const float*)d_in[2];
    const float* w5      = (const float*)d_in[3];
    const float* w7      = (const float*)d_in[4];
    const float* bn1_g   = (const float*)d_in[5];
    const float* bn1_b   = (const float*)d_in[6];
    const float* bn1_m   = (const float*)d_in[7];
    const float* bn1_v   = (const float*)d_in[8];
    const float* sconv_w = (const float*)d_in[9];
    const float* gate_w  = (const float*)d_in[10];
    const float* gate_b  = (const float*)d_in[11];
    const float* exp_w   = (const float*)d_in[12];
    const float* exp_b   = (const float*)d_in[13];
    const float* ebn_g   = (const float*)d_in[14];
    const float* ebn_b   = (const float*)d_in[15];
    const float* ebn_m   = (const float*)d_in[16];
    const float* ebn_v   = (const float*)d_in[17];
    const float* fc_w    = (const float*)d_in[18];
    const float* fc_b    = (const float*)d_in[19];

    float* out       = (float*)d_out;
    float* feats_out = out;                     // (256, 384)
    float* logp_out  = out + B_ * FEAT_;        // (256, 9)

    fb_fused<<<B_, NTH, 0, stream>>>(x, fir, w3, w5, w7,
                                     bn1_g, bn1_b, bn1_m, bn1_v, sconv_w,
                                     gate_w, gate_b, exp_w, exp_b,
                                     ebn_g, ebn_b, ebn_m, ebn_v,
                                     fc_w, fc_b, feats_out, logp_out);
}